// Round 1
// 349.407 us; speedup vs baseline: 1.0000x; 1.0000x over previous
//
#include <hip/hip_runtime.h>
#include <hip/hip_bf16.h>
#include <stdint.h>

// ---------------------------------------------------------------------------
// 2-layer GAT (inference) on MI355X, dtype-adaptive.
// Round-15 changes vs round-14 (349.4 us):
//  * aggregate4: gather widened to 16B/lane (dwordx4), 32 lanes per edge row,
//    TWO edges in flight per wave-iteration (halves VMEM instr count, doubles
//    bytes-in-flight); halves combined via one shfl_xor(32) per accumulator.
//  * aggregate1: same treatment — 8 lanes x 16B per row, 8 edge slots
//    (was 4 slots x 8B), combine via shfl_xor(8/16/32).
//  * detect_kernel parallelized to 64 lanes + ballot (was 1 thread doing 128
//    serial cold loads).
// Everything else byte-identical to round 14.
// ---------------------------------------------------------------------------

typedef __attribute__((ext_vector_type(8))) short bf16x8;
typedef __attribute__((ext_vector_type(8))) unsigned short u16x8;
typedef __attribute__((ext_vector_type(4))) float f32x4;

__device__ __forceinline__ float bf2f(__hip_bfloat16 v) { return __bfloat162float(v); }
__device__ __forceinline__ float bfbits2f(unsigned short s) {
  union { uint32_t u; float f; } v; v.u = ((uint32_t)s) << 16; return v.f;
}
__device__ __forceinline__ unsigned short f2bfbits(float f) {
  union { float f; uint32_t u; } v; v.f = f;
  uint32_t u = v.u;
  return (unsigned short)((u + 0x7fffu + ((u >> 16) & 1u)) >> 16);  // RNE
}

template <bool BF>
__device__ __forceinline__ float loadF(const void* p, size_t i) {
  if (BF) return bf2f(((const __hip_bfloat16*)p)[i]);
  return ((const float*)p)[i];
}
template <bool BF>
__device__ __forceinline__ void storeF(void* p, size_t i, float v) {
  if (BF) ((__hip_bfloat16*)p)[i] = __float2bfloat16(v);
  else    ((float*)p)[i] = v;
}
template <bool I64>
__device__ __forceinline__ int loadI(const void* p, size_t i) {
  if (I64) return (int)((const long long*)p)[i];
  return ((const int*)p)[i];
}
__device__ __forceinline__ float lrelu(float v) { return fmaxf(v, 0.2f * v); }

// ----------------- dtype detection (wave-parallel) -------------------------
__global__ void detect_kernel(const uint32_t* __restrict__ xbits,
                              const uint32_t* __restrict__ eibits,
                              int* __restrict__ flags) {
  const int l = threadIdx.x;  // 64 threads
  uint32_t u = xbits[l];
  uint32_t e = (u >> 23) & 0xffu;
  bool plausible = (e < 160u && e > 90u) || (u & 0x7fffffffu) == 0u;
  unsigned long long m1 = __ballot(plausible);
  bool z = (eibits[2 * l + 1] == 0u);
  unsigned long long m2 = __ballot(z);
  if (l == 0) {
    flags[0] = (__popcll(m1) < 32) ? 1 : 0;  // 1 = floats are bf16
    flags[1] = (m2 == ~0ULL) ? 1 : 0;        // 1 = edge_index is int64
  }
}

// ----------------- prep (single dispatch): cast x; transpose W1, W2 --------
__global__ __launch_bounds__(256) void prep_all(
    const void* __restrict__ x, unsigned short* __restrict__ xb, size_t nx,
    const void* __restrict__ W1, unsigned short* __restrict__ w1t, int K1, int N1,
    const void* __restrict__ W2, unsigned short* __restrict__ w2t, int K2, int N2,
    int nb_cast, int nb_t1, const int* __restrict__ flags) {
  const int b = blockIdx.x;
  const bool f = flags[0] != 0;
  if (b < nb_cast) {
    size_t i = ((size_t)b * 256 + threadIdx.x) * 4;
    if (i >= nx) return;
    ushort4 o;
    if (f) {
      o = *(const ushort4*)((const unsigned short*)x + i);
    } else {
      float4 v = *(const float4*)((const float*)x + i);
      o.x = f2bfbits(v.x); o.y = f2bfbits(v.y);
      o.z = f2bfbits(v.z); o.w = f2bfbits(v.w);
    }
    *(ushort4*)(xb + i) = o;
  } else if (b < nb_cast + nb_t1) {
    int idx = (b - nb_cast) * 256 + threadIdx.x;
    if (idx >= K1 * N1) return;
    int k = idx / N1, n = idx - k * N1;
    float v = f ? loadF<true>(W1, idx) : loadF<false>(W1, idx);
    w1t[(size_t)n * K1 + k] = f2bfbits(v);
  } else {
    int idx = (b - nb_cast - nb_t1) * 256 + threadIdx.x;
    if (idx >= K2 * N2) return;
    int k = idx / N2, n = idx - k * N2;
    float v = f ? loadF<true>(W2, idx) : loadF<false>(W2, idx);
    w2t[(size_t)n * K2 + k] = f2bfbits(v);
  }
}

// ----------------- MFMA GEMM + fused attention-dot epilogue ----------------
template <int KC, int NT, int HB>
__global__ __launch_bounds__(256, 4) void gemm_mfma_att(
    const unsigned short* __restrict__ A,   // [M][KC] bf16 bits
    const unsigned short* __restrict__ BT,  // [Htot*64][KC] bf16 bits
    unsigned short* __restrict__ C,         // [M][Htot*64] bf16 bits
    const void* __restrict__ att_s, const void* __restrict__ att_d,
    float* __restrict__ as_o, float* __restrict__ ad_o,
    float* __restrict__ wself_o,
    int M, int Htot, const int* __restrict__ flags) {
  const int lane = threadIdx.x & 63;
  const int col = lane & 15;
  const int quad = lane >> 4;
  const int m0 = blockIdx.x * 64 + (threadIdx.x >> 6) * 16;
  const int n0 = blockIdx.y * (NT * 16);
  const int NCOL = Htot * 64;

  int gm = m0 + col;                 // A row this lane supplies
  if (gm > M - 1) gm = M - 1;        // clamp: garbage only affects guarded rows
  const unsigned short* arow = A + (size_t)gm * KC + quad * 8;
  const unsigned short* bbase = BT + (size_t)(n0 + col) * KC + quad * 8;

  f32x4 acc[NT] = {};
#pragma unroll
  for (int k0 = 0; k0 < KC; k0 += 32) {
    bf16x8 a = *(const bf16x8*)(arow + k0);
#pragma unroll
    for (int s = 0; s < NT; s++) {
      bf16x8 b = *(const bf16x8*)(bbase + (size_t)s * 16 * KC + k0);
      acc[s] = __builtin_amdgcn_mfma_f32_16x16x32_bf16(a, b, acc[s], 0, 0, 0);
    }
  }
  // store C
#pragma unroll
  for (int s = 0; s < NT; s++)
#pragma unroll
    for (int r = 0; r < 4; r++) {
      int m = m0 + quad * 4 + r;
      if (m < M) C[(size_t)m * NCOL + n0 + s * 16 + col] = f2bfbits(acc[s][r]);
    }
  // fused attention dots: head h covers s in [h*SC, (h+1)*SC)
  const int SC = NT / HB;
  const bool f = flags[0] != 0;
#pragma unroll
  for (int h = 0; h < HB; h++) {
    const int gh = blockIdx.y * HB + h;
    float ps[4] = {0.f, 0.f, 0.f, 0.f};
    float pd[4] = {0.f, 0.f, 0.f, 0.f};
#pragma unroll
    for (int j = 0; j < SC; j++) {
      int s = h * SC + j;
      int ci = gh * 64 + j * 16 + col;
      float av = f ? loadF<true>(att_s, ci) : loadF<false>(att_s, ci);
      float dv = f ? loadF<true>(att_d, ci) : loadF<false>(att_d, ci);
#pragma unroll
      for (int r = 0; r < 4; r++) {
        ps[r] += acc[s][r] * av;
        pd[r] += acc[s][r] * dv;
      }
    }
#pragma unroll
    for (int o = 1; o < 16; o <<= 1) {
#pragma unroll
      for (int r = 0; r < 4; r++) {
        ps[r] += __shfl_xor(ps[r], o);
        pd[r] += __shfl_xor(pd[r], o);
      }
    }
    if (col == 0) {
#pragma unroll
      for (int r = 0; r < 4; r++) {
        int m = m0 + quad * 4 + r;
        if (m < M) {
          as_o[m * Htot + gh] = ps[r];
          ad_o[m * Htot + gh] = pd[r];
          wself_o[m * Htot + gh] = __expf(lrelu(ps[r] + pd[r]));  // no max-sub
        }
      }
    }
  }
}

// ----------------- CSR build ------------------------------------------------
__global__ void hist_kernel(const void* __restrict__ ei, int E,
                            int* __restrict__ deg, const int* __restrict__ flags) {
  int e = blockIdx.x * blockDim.x + threadIdx.x;
  if (e >= E) return;
  int d = flags[1] ? loadI<true>(ei, (size_t)E + e) : loadI<false>(ei, (size_t)E + e);
  atomicAdd(&deg[d], 1);
}

__global__ __launch_bounds__(256) void scan_block_sums(const int* __restrict__ deg,
                                                       int* __restrict__ bsum, int n) {
  __shared__ int buf[256];
  const int t = threadIdx.x;
  const int i = blockIdx.x * 256 + t;
  buf[t] = (i < n) ? deg[i] : 0;
  __syncthreads();
  for (int o = 128; o > 0; o >>= 1) {
    if (t < o) buf[t] += buf[t + o];
    __syncthreads();
  }
  if (t == 0) bsum[blockIdx.x] = buf[0];
}

__global__ __launch_bounds__(256) void scan_bsums(int* __restrict__ bsum, int nb) {
  __shared__ int buf[256];
  const int t = threadIdx.x;
  int orig = (t < nb) ? bsum[t] : 0;
  buf[t] = orig;
  __syncthreads();
  for (int o = 1; o < 256; o <<= 1) {
    int v = (t >= o) ? buf[t - o] : 0;
    __syncthreads();
    buf[t] += v;
    __syncthreads();
  }
  if (t < nb) bsum[t] = buf[t] - orig;  // exclusive
}

__global__ __launch_bounds__(256) void scan_finalize(const int* __restrict__ deg,
                                                     const int* __restrict__ bsum,
                                                     int* __restrict__ row_start, int n) {
  __shared__ int buf[256];
  const int t = threadIdx.x;
  const int i = blockIdx.x * 256 + t;
  int v = (i < n) ? deg[i] : 0;
  buf[t] = v;
  __syncthreads();
  for (int o = 1; o < 256; o <<= 1) {
    int x = (t >= o) ? buf[t - o] : 0;
    __syncthreads();
    buf[t] += x;
    __syncthreads();
  }
  if (i < n) row_start[i + 1] = bsum[blockIdx.x] + buf[t];
  if (i == 0) row_start[0] = 0;
}

__global__ void scatter_edges(const void* __restrict__ ei, int E,
                              const int* __restrict__ row_start,
                              int* __restrict__ cursor, int* __restrict__ col_src,
                              int* __restrict__ col_dst,
                              const int* __restrict__ flags) {
  int e = blockIdx.x * blockDim.x + threadIdx.x;
  if (e >= E) return;
  int s, d;
  if (flags[1]) { s = loadI<true>(ei, e);  d = loadI<true>(ei, (size_t)E + e); }
  else          { s = loadI<false>(ei, e); d = loadI<false>(ei, (size_t)E + e); }
  int pos = atomicAdd(&cursor[d], 1);
  int idx = row_start[d] + pos;
  col_src[idx] = s;
  col_dst[idx] = d;
}

// ----------------- edge-parallel softmax weights (coalesced map) -----------
__global__ __launch_bounds__(256) void weight4(
    const int* __restrict__ col_src, const int* __restrict__ col_dst,
    const float4* __restrict__ as4, const float4* __restrict__ ad4,
    float4* __restrict__ wbuf, int E) {
  int e = blockIdx.x * 256 + threadIdx.x;
  if (e >= E) return;
  float4 a = as4[col_src[e]];
  float4 b = ad4[col_dst[e]];
  float4 w;
  w.x = __expf(lrelu(a.x + b.x));
  w.y = __expf(lrelu(a.y + b.y));
  w.z = __expf(lrelu(a.z + b.z));
  w.w = __expf(lrelu(a.w + b.w));
  wbuf[e] = w;
}

__global__ __launch_bounds__(256) void weight1(
    const int* __restrict__ col_src, const int* __restrict__ col_dst,
    const float* __restrict__ as_, const float* __restrict__ ad_,
    float* __restrict__ wbuf, int E) {
  int e = blockIdx.x * 256 + threadIdx.x;
  if (e >= E) return;
  wbuf[e] = __expf(lrelu(as_[col_src[e]] + ad_[col_dst[e]]));
}

// ----------------- aggregation: weighted gather + inline denominator -------
// H=4: 16B/lane gather, 32 lanes per edge row, 2 edges per wave-iteration.
// Lane l: j = l&31 covers cols 8j..8j+7 (head j>>3); half = l>>5 picks the
// edge of the pair. Halves combined via shfl_xor(32) at the end.
__global__ __launch_bounds__(256) void aggregate4(
    const unsigned short* __restrict__ h_in,   // [N][256] bf16 bits
    const float* __restrict__ wselfA,
    const float* __restrict__ wbuf,            // [E][4]
    const int* __restrict__ row_start, const int* __restrict__ col_src,
    const void* __restrict__ bias,
    unsigned short* __restrict__ out,          // [N][256] bf16 bits
    int N, const int* __restrict__ flags) {
  const int dst = blockIdx.x * 4 + (threadIdx.x >> 6);
  if (dst >= N) return;
  const int l = threadIdx.x & 63;
  const int j = l & 31;          // column group: cols 8j..8j+7
  const int half = l >> 5;       // which edge of the pair
  const int h = j >> 3;          // head
  const int rs = row_start[dst];
  const int dg = row_start[dst + 1] - rs;
  const float ws = wselfA[dst * 4 + h];

  float a[8];
  {
    u16x8 sv = *(const u16x8*)(h_in + (size_t)dst * 256 + 8 * j);
    const float s = half ? 0.f : ws;   // self contribution from half 0 only
#pragma unroll
    for (int r = 0; r < 8; r++) a[r] = s * bfbits2f(sv[r]);
  }
  float p = 0.f;
#pragma unroll 4
  for (int i = 0; i < dg; i += 2) {
    const int ii = i + half;
    const bool act = ii < dg;                 // odd-degree tail guard
    const int idx = rs + (act ? ii : (dg - 1));
    const int sn = col_src[idx];
    const float w = act ? wbuf[(size_t)idx * 4 + h] : 0.f;
    p += w;
    u16x8 sv = *(const u16x8*)(h_in + (size_t)sn * 256 + 8 * j);
#pragma unroll
    for (int r = 0; r < 8; r++) a[r] += w * bfbits2f(sv[r]);
  }
#pragma unroll
  for (int r = 0; r < 8; r++) a[r] += __shfl_xor(a[r], 32);
  p += __shfl_xor(p, 32);

  if (half == 0) {
    const float inv = 1.0f / (p + ws + 1e-16f);
    const bool f = flags[0] != 0;
    u16x8 ov;
#pragma unroll
    for (int r = 0; r < 8; r++) {
      float b = f ? loadF<true>(bias, 8 * j + r) : loadF<false>(bias, 8 * j + r);
      float o = a[r] * inv + b;
      o = o > 0.f ? o : __expf(o) - 1.f;      // elu
      ov[r] = f2bfbits(o);
    }
    *(u16x8*)(out + (size_t)dst * 256 + 8 * j) = ov;
  }
}

// H=1: 16B/lane gather, 8 lanes per edge row, 8 edge slots per wave.
// Lane l: el = l&7 covers cols 8el..8el+7; slot = l>>3 strides the edges.
// Slots combined via shfl_xor(8/16/32).
__global__ __launch_bounds__(256) void aggregate1(
    const unsigned short* __restrict__ h_in,   // [N][64] bf16 bits
    const float* __restrict__ wselfA,
    const float* __restrict__ wbuf,            // [E]
    const int* __restrict__ row_start, const int* __restrict__ col_src,
    const void* __restrict__ bias,
    void* __restrict__ out, int N, const int* __restrict__ flags) {
  const int dst = blockIdx.x * 4 + (threadIdx.x >> 6);
  if (dst >= N) return;
  const int l = threadIdx.x & 63;
  const int el = l & 7;
  const int slot = l >> 3;
  const int rs = row_start[dst];
  const int dg = row_start[dst + 1] - rs;
  const float ws = wselfA[dst];

  float a[8];
  {
    u16x8 sv = *(const u16x8*)(h_in + (size_t)dst * 64 + 8 * el);
    const float s = (slot == 0) ? ws : 0.f;
#pragma unroll
    for (int r = 0; r < 8; r++) a[r] = s * bfbits2f(sv[r]);
  }
  float p = 0.f;
#pragma unroll 2
  for (int i = slot; i < dg; i += 8) {
    const int sn = col_src[rs + i];
    const float w = wbuf[rs + i];
    p += w;
    u16x8 sv = *(const u16x8*)(h_in + (size_t)sn * 64 + 8 * el);
#pragma unroll
    for (int r = 0; r < 8; r++) a[r] += w * bfbits2f(sv[r]);
  }
#pragma unroll
  for (int o = 8; o < 64; o <<= 1) {
#pragma unroll
    for (int r = 0; r < 8; r++) a[r] += __shfl_xor(a[r], o);
    p += __shfl_xor(p, o);
  }

  if (slot == 0) {
    const float inv = 1.0f / (p + ws + 1e-16f);
    const bool f = flags[0] != 0;
    float o[8];
#pragma unroll
    for (int r = 0; r < 8; r++) {
      float b = f ? loadF<true>(bias, 8 * el + r) : loadF<false>(bias, 8 * el + r);
      o[r] = a[r] * inv + b;
    }
    const size_t ob = (size_t)dst * 64 + 8 * el;
    if (f) {
      u16x8 ov;
#pragma unroll
      for (int r = 0; r < 8; r++) ov[r] = f2bfbits(o[r]);
      *(u16x8*)((unsigned short*)out + ob) = ov;
    } else {
      float4 v0, v1;
      v0.x = o[0]; v0.y = o[1]; v0.z = o[2]; v0.w = o[3];
      v1.x = o[4]; v1.y = o[5]; v1.z = o[6]; v1.w = o[7];
      *(float4*)((float*)out + ob) = v0;
      *(float4*)((float*)out + ob + 4) = v1;
    }
  }
}

// ---------------------------------------------------------------------------
extern "C" void kernel_launch(void* const* d_in, const int* in_sizes, int n_in,
                              void* d_out, int out_size, void* d_ws, size_t ws_size,
                              hipStream_t stream) {
  const void* x    = d_in[0];
  const void* ei   = d_in[1];
  const void* W1   = d_in[2];
  const void* as1w = d_in[3];
  const void* ad1w = d_in[4];
  const void* b1   = d_in[5];
  const void* W2   = d_in[6];
  const void* as2w = d_in[7];
  const void* ad2w = d_in[8];
  const void* b2   = d_in[9];

  const int N  = out_size / 64;      // 50000
  const int F  = in_sizes[0] / N;    // 128
  const int E  = in_sizes[1] / 2;    // 800000
  const int H1 = in_sizes[3] / 64;   // 4
  const int D1 = H1 * 64;            // 256
  const int D2 = 64;                 // layer-2 output dim (H2 = 1)

  size_t off = 0;
  auto alloc = [&](size_t bytes) -> void* {
    void* p = (char*)d_ws + off;
    off += (bytes + 255) & ~(size_t)255;
    return p;
  };
  int* flags = (int*)alloc(2 * sizeof(int));
  __hip_bfloat16* h1 = (__hip_bfloat16*)alloc((size_t)N * D1 * 2);
  __hip_bfloat16* x2 = (__hip_bfloat16*)alloc((size_t)N * D1 * 2);
  __hip_bfloat16* h2 = h1;  // h1 dead after layer-1 aggregate; reuse
  unsigned short* xb  = (unsigned short*)alloc((size_t)N * F * 2);   // x in bf16
  unsigned short* w1t = (unsigned short*)alloc((size_t)D1 * F * 2);  // [256][128]
  unsigned short* w2t = (unsigned short*)alloc((size_t)D2 * D1 * 2); // [64][256]
  float* as1 = (float*)alloc((size_t)N * H1 * 4);
  float* ad1 = (float*)alloc((size_t)N * H1 * 4);
  float* wself1 = (float*)alloc((size_t)N * H1 * 4);
  float* as2 = (float*)alloc((size_t)N * 4);
  float* ad2 = (float*)alloc((size_t)N * 4);
  float* wself2 = (float*)alloc((size_t)N * 4);
  int* zero_region = (int*)alloc((size_t)2 * N * 4);  // deg | cursor
  int* deg = zero_region;
  int* cursor = zero_region + N;
  int* row_start = (int*)alloc((size_t)(N + 1) * 4);
  int* col_src = (int*)alloc((size_t)E * 4);
  int* col_dst = (int*)alloc((size_t)E * 4);
  float* wbuf = (float*)alloc((size_t)E * 4 * 4);  // L1: [E]float4; L2 reuses [E]float
  int* bsum = (int*)alloc((size_t)256 * 4);
  (void)ws_size; (void)n_in;

  const int nb = (N + 255) / 256;
  const int eb = (E + 255) / 256;
  const int db = (N + 3) / 4;
  const int gb = (N + 63) / 64;

  // ---- dtype detection + CSR build + GEMM prep (single prep dispatch)
  detect_kernel<<<1, 64, 0, stream>>>((const uint32_t*)x, (const uint32_t*)ei, flags);
  hipMemsetAsync(zero_region, 0, (size_t)2 * N * 4, stream);
  hist_kernel<<<eb, 256, 0, stream>>>(ei, E, deg, flags);
  scan_block_sums<<<nb, 256, 0, stream>>>(deg, bsum, N);
  scan_bsums<<<1, 256, 0, stream>>>(bsum, nb);
  scan_finalize<<<nb, 256, 0, stream>>>(deg, bsum, row_start, N);
  scatter_edges<<<eb, 256, 0, stream>>>(ei, E, row_start, cursor, col_src, col_dst, flags);

  const size_t nx = (size_t)N * F;
  const int nb_cast = (int)((nx / 4 + 255) / 256);
  const int nb_t1 = (F * D1 + 255) / 256;
  const int nb_t2 = (D1 * D2 + 255) / 256;
  prep_all<<<nb_cast + nb_t1 + nb_t2, 256, 0, stream>>>(
      x, xb, nx, W1, w1t, F, D1, W2, w2t, D1, D2, nb_cast, nb_t1, flags);

  // ---- layer 1: GEMM 64x128 tiles (grid.y = 2), K=128 unrolled
  gemm_mfma_att<128, 8, 2><<<dim3(gb, 2), 256, 0, stream>>>(
      xb, w1t, (unsigned short*)h1, as1w, ad1w, as1, ad1, wself1, N, H1, flags);
  weight4<<<eb, 256, 0, stream>>>(col_src, col_dst, (const float4*)as1,
                                  (const float4*)ad1, (float4*)wbuf, E);
  aggregate4<<<db, 256, 0, stream>>>((const unsigned short*)h1, wself1, wbuf,
                                     row_start, col_src, b1,
                                     (unsigned short*)x2, N, flags);

  // ---- layer 2: GEMM 64x64 tile, K=256 unrolled
  gemm_mfma_att<256, 4, 1><<<dim3(gb, 1), 256, 0, stream>>>(
      (const unsigned short*)x2, w2t, (unsigned short*)h2, as2w, ad2w,
      as2, ad2, wself2, N, 1, flags);
  weight1<<<eb, 256, 0, stream>>>(col_src, col_dst, as2, ad2, wbuf, E);
  aggregate1<<<db, 256, 0, stream>>>((const unsigned short*)h2, wself2, wbuf,
                                     row_start, col_src, b2, d_out, N, flags);
}